// Round 5
// baseline (2998.117 us; speedup 1.0000x reference)
//
#include <hip/hip_runtime.h>
#include <math.h>

namespace {
constexpr int kB = 512;
constexpr int kT = 256;
constexpr int kD = 256;
constexpr int kS = 8;
constexpr int kStRow = 292;  // 288 data (physk layout) + 4; 292 % 32 == 4
constexpr int kRedRow = 20;  // reduction table row stride: 16 wave slots + pad

__device__ __forceinline__ int physk(int k) { return k + ((k >> 5) << 2); }

// DPP cross-lane adds (VALU pipe — zero DS traffic). HW-validated R2-R4.
//   0xB1  quad_perm [1,0,3,2]  == xor 1
//   0x4E  quad_perm [2,3,0,1]  == xor 2
//   0x141 row_half_mirror      == xor 7 (full 8-lane sum once quads uniform)
template <int CTRL>
__device__ __forceinline__ float dpp_add(float v) {
  int p = __builtin_amdgcn_update_dpp(0, __float_as_int(v), CTRL, 0xF, 0xF, false);
  return v + __int_as_float(p);
}
}

// ---------------------------------------------------------------------------
// Kernel A: XW[b,t,:] = inputs[b,t,:] @ W, skipping t >= lengths[b]. (unchanged)
// ---------------------------------------------------------------------------
__global__ __launch_bounds__(256, 2)
void xw_gemm_kernel(const float* __restrict__ X, const float* __restrict__ W,
                    const int* __restrict__ lengths, float* __restrict__ XW) {
  const int m0 = blockIdx.x * 32;
  const int b = m0 >> 8;
  const int t0 = m0 & 255;
  if (t0 >= lengths[b]) return;

  __shared__ float Xs[32][kD];
  const int tid = threadIdx.x;
  const int j  = tid & 63;
  const int rg = tid >> 6;

  const float4* Xg4 = (const float4*)(X + (size_t)m0 * kD);
  float4* Xs4 = (float4*)&Xs[0][0];
  for (int i = tid; i < 32 * kD / 4; i += 256) Xs4[i] = Xg4[i];
  __syncthreads();

  float4 acc[8];
#pragma unroll
  for (int i = 0; i < 8; ++i) acc[i] = make_float4(0.f, 0.f, 0.f, 0.f);

  const float4* W4 = (const float4*)W;
  const float4* Xrow = (const float4*)&Xs[rg * 8][0];

  for (int k4 = 0; k4 < kD / 4; ++k4) {
    float4 w0 = W4[(size_t)(4 * k4 + 0) * 64 + j];
    float4 w1 = W4[(size_t)(4 * k4 + 1) * 64 + j];
    float4 w2 = W4[(size_t)(4 * k4 + 2) * 64 + j];
    float4 w3 = W4[(size_t)(4 * k4 + 3) * 64 + j];
#pragma unroll
    for (int i = 0; i < 8; ++i) {
      float4 x = Xrow[i * 64 + k4];
      acc[i].x = fmaf(x.x, w0.x, fmaf(x.y, w1.x, fmaf(x.z, w2.x, fmaf(x.w, w3.x, acc[i].x))));
      acc[i].y = fmaf(x.x, w0.y, fmaf(x.y, w1.y, fmaf(x.z, w2.y, fmaf(x.w, w3.y, acc[i].y))));
      acc[i].z = fmaf(x.x, w0.z, fmaf(x.y, w1.z, fmaf(x.z, w2.z, fmaf(x.w, w3.z, acc[i].z))));
      acc[i].w = fmaf(x.x, w0.w, fmaf(x.y, w1.w, fmaf(x.z, w2.w, fmaf(x.w, w3.w, acc[i].w))));
    }
  }
  float4* XW4 = (float4*)XW;
#pragma unroll
  for (int i = 0; i < 8; ++i)
    XW4[(size_t)(m0 + rg * 8 + i) * 64 + j] = acc[i];
}

// ---------------------------------------------------------------------------
// Kernel B: GK[b,t,s] = inputs[b,t,:] . keys[s,:], t < lengths[b] only. (unchanged)
// ---------------------------------------------------------------------------
__global__ __launch_bounds__(256, 4)
void gk_kernel(const float* __restrict__ inputs, const float* __restrict__ keys,
               const int* __restrict__ lengths, float* __restrict__ GK) {
  const int b = blockIdx.x;
  const int tid = threadIdx.x;
  const int lane = tid & 63;
  const int wid = tid >> 6;
  const int len = lengths[b];

  __shared__ float4 Ks4[kS * 64];
  for (int i = tid; i < kS * 64; i += 256) Ks4[i] = ((const float4*)keys)[i];
  __syncthreads();

  const float4* X4 = (const float4*)inputs;
  for (int t = wid; t < len; t += 4) {
    float4 x = X4[((size_t)b * kT + t) * 64 + lane];
    float p[kS];
#pragma unroll
    for (int s = 0; s < kS; ++s) {
      float4 kk = Ks4[s * 64 + lane];
      p[s] = fmaf(x.x, kk.x, fmaf(x.y, kk.y, fmaf(x.z, kk.z, x.w * kk.w)));
    }
#pragma unroll
    for (int off = 32; off >= 1; off >>= 1) {
#pragma unroll
      for (int s = 0; s < kS; ++s) p[s] += __shfl_xor(p[s], off, 64);
    }
    if (lane == 0) {
      float* g = GK + ((size_t)b * kT + t) * kS;
#pragma unroll
      for (int s = 0; s < kS; ++s) g[s] = p[s];
    }
  }
}

// ---------------------------------------------------------------------------
// Kernel S: rank lengths descending (stable). order[r] = batch with rank r.
// ---------------------------------------------------------------------------
__global__ __launch_bounds__(512)
void sort_lengths_kernel(const int* __restrict__ lengths, int* __restrict__ order) {
  __shared__ int L[kB];
  const int i = threadIdx.x;
  L[i] = lengths[i];
  __syncthreads();
  const int li = L[i];
  int r = 0;
  for (int j = 0; j < kB; ++j) {
    const int lj = L[j];
    r += (lj > li || (lj == li && j < i)) ? 1 : 0;
  }
  order[r] = i;
}

// ---------------------------------------------------------------------------
// Kernel C (rec8): 256 blocks x 1024 threads, paired sorted batches.
// R4 post-mortem: rec7 still ~18 floats/thread over the 128-reg unified
// budget (WRITE 3.0GB residual scratch). rec8 cuts cross-barrier liveness
// STRUCTURALLY via DEFERRED NORMALIZATION:
//   State is stored UNNORMALIZED in LDS; per-row 1/norm comes from the redN
//   partial table, read back at the START of the next step (phase 1). All
//   consumers are linear in the state, so the scale commutes:
//     matmul: scale selected C by inh[q] after the k-reduction;
//     gate:   scale the summed dot once at finalize;
//     update: sr = st_un * inh (2 elements).
//   This DELETES barrier B2 (3 -> 2 barriers/step) and the h/sr loop-carried
//   registers. Cross-B1 live set ~95 = rec3's proven spill-free level.
// First step is primed with redN slots = 1/16 (norm 1 -> state = keys, the
// reference's zero_state). Final out applies the last inh per row.
// Everything HW-proven retained: u2[32] U slice, DPP {xor1,xor2,mirror7}
// k-reduction, q*36 conflict-free state addressing, sorted pairing,
// halved (8-slot + shfl8) table readbacks. expm1f -> __expf-1 (err ~1e-7).
// ---------------------------------------------------------------------------
__global__ __launch_bounds__(1024, 4)
void dynmem_rec8_kernel(const float* __restrict__ inputs,   // [B,T,D]
                        const int*   __restrict__ lengths,  // [B]
                        const float* __restrict__ keys,     // [S,D]
                        const float* __restrict__ U,        // [D,D]
                        const float* __restrict__ V,        // [D,D]
                        const float* __restrict__ gate_bias,
                        const float* __restrict__ state_bias,
                        const float* __restrict__ XW,       // [B,T,D]
                        const float* __restrict__ GK,       // [B,T,S]
                        const int*   __restrict__ order,    // [B] desc by length
                        float* __restrict__ out)            // [B,S,D]
{
  const int blk = blockIdx.x;
  const int bA = order[blk];
  const int bB = order[kB - 1 - blk];
  const int tid = threadIdx.x;
  const int w = tid >> 6;        // 0..15
  const int lane = tid & 63;
  const int q = lane & 7;        // k-chunk AND the state row this lane owns
  const int jj = lane >> 3;      // 0..7
  const int p = w * 8 + jj;      // col-pair index, 0..127
  const int c0 = 2 * p;
  const int c0p = physk(c0);     // both cols in same 32-group (c0 even)
  const int hoff = lane & 8;     // which 8-slot half of the red tables

  __shared__ float StA[kS * kStRow];
  __shared__ float StB[kS * kStRow];
  __shared__ float KVL[kS * kD];
  __shared__ float redGA[kS * kRedRow], redGB[kS * kRedRow];
  __shared__ float redNA[kS * kRedRow], redNB[kS * kRedRow];
  __shared__ float inhFA[kS], inhFB[kS];

  // init both states = keys (padded layout, UNNORMALIZED with inh primed = 1)
  for (int i = tid; i < kS * kD; i += 1024) {
    int s = i >> 8, dd = i & 255;
    float kv = keys[i];
    int pa = s * kStRow + physk(dd);
    StA[pa] = kv;
    StB[pa] = kv;
  }
  // prime redN so the first readback yields norm 1 (16 slots of 1/16)
  for (int i = tid; i < kS * 16; i += 1024) {
    int s = i >> 4, ww = i & 15;
    redNA[s * kRedRow + ww] = 0.0625f;
    redNB[s * kRedRow + ww] = 0.0625f;
  }

  // persistent U slice: rows q*32..q*32+31, cols c0..c0+1  (64 regs)
  float2 u2[32];
#pragma unroll
  for (int kk = 0; kk < 32; ++kk)
    u2[kk] = *(const float2*)(U + (size_t)(q * 32 + kk) * kD + c0);

  // KV[s][d] = (keys @ V)[s][d] + state_bias[d]; thread (h4,d) does rows h4, h4+4.
  {
    const int h4 = tid >> 8, d = tid & 255;   // h4 in 0..3
    float a0 = 0.f, a1 = 0.f;
    const float* Vc = V + d;
    const float* K0 = keys + (size_t)h4 * kD;
    const float* K1 = keys + (size_t)(h4 + 4) * kD;
    for (int k = 0; k < kD; ++k) {
      float v = Vc[(size_t)k * kD];
      a0 = fmaf(K0[k], v, a0);
      a1 = fmaf(K1[k], v, a1);
    }
    float sb = state_bias[d];
    KVL[h4 * kD + d] = a0 + sb;
    KVL[(h4 + 4) * kD + d] = a1 + sb;
  }

  const float gb = gate_bias[0];
  int lenA = lengths[bA]; lenA = lenA < 0 ? 0 : (lenA > kT ? kT : lenA);
  int lenB = lengths[bB]; lenB = lenB < 0 ? 0 : (lenB > kT ? kT : lenB);
  // sorted desc => lenA >= lenB

  __syncthreads();  // states + KVL + primed tables ready

  const float2 kvq = *(const float2*)(KVL + q * kD + c0);
  const float* SA = StA + q * 36;  // physical base of 32-k chunk q within a row
  const float* SB = StB + q * 36;
  float* stpA = StA + q * kStRow + c0p;  // this thread's own state slot
  float* stpB = StB + q * kStRow + c0p;

  for (int t = 0; t < lenA; ++t) {
    const bool dB = t < lenB;
    const size_t baseA = ((size_t)bA * kT + t) * (size_t)kD;
    const size_t baseB = ((size_t)bB * kT + t) * (size_t)kD;

    // ================= Phase 1 (reads state; writes redG) =================
    // inverse-norm readback (table written last step / primed)
    float inhA, inhB = 1.f;
    {
      const float* rn = redNA + q * kRedRow + hoff;
      float4 na = *(const float4*)(rn);
      float4 nb = *(const float4*)(rn + 4);
      float nh = ((na.x + na.y) + (na.z + na.w)) + ((nb.x + nb.y) + (nb.z + nb.w));
      float ns = nh + __shfl_xor(nh, 8, 64);
      inhA = 1.f / fmaxf(sqrtf(ns), 1e-12f);
    }
    if (dB) {
      const float* rn = redNB + q * kRedRow + hoff;
      float4 na = *(const float4*)(rn);
      float4 nb = *(const float4*)(rn + 4);
      float nh = ((na.x + na.y) + (na.z + na.w)) + ((nb.x + nb.y) + (nb.z + nb.w));
      float ns = nh + __shfl_xor(nh, 8, 64);
      inhB = 1.f / fmaxf(sqrtf(ns), 1e-12f);
    }

    // own unnormalized state (intact until our own write in phase 2)
    const float2 stA2 = *(const float2*)stpA;
    float2 stB2 = make_float2(0.f, 0.f);
    if (dB) stB2 = *(const float2*)stpB;

    // gate partials (unnormalized dot; scaled once at finalize)
    {
      float2 xA = *(const float2*)(inputs + baseA + c0);
      float pg = fmaf(xA.x, stA2.x, xA.y * stA2.y);
      pg += __shfl_xor(pg, 8, 64);
      pg += __shfl_xor(pg, 16, 64);
      pg += __shfl_xor(pg, 32, 64);
      if (lane < 8) redGA[lane * kRedRow + w] = pg;  // lane == q here
    }
    if (dB) {
      float2 xB = *(const float2*)(inputs + baseB + c0);
      float pg = fmaf(xB.x, stB2.x, xB.y * stB2.y);
      pg += __shfl_xor(pg, 8, 64);
      pg += __shfl_xor(pg, 16, 64);
      pg += __shfl_xor(pg, 32, 64);
      if (lane < 8) redGB[lane * kRedRow + w] = pg;
    }

    // ---- matmul A on unnormalized state (U in registers) ----
    float caA, cbA, caB = 0.f, cbB = 0.f;
    {
      float C0[8], C1[8];
#pragma unroll
      for (int s = 0; s < 8; ++s) { C0[s] = 0.f; C1[s] = 0.f; }
#pragma unroll
      for (int k4 = 0; k4 < 8; ++k4) {
#pragma unroll
        for (int s = 0; s < 8; ++s) {
          float4 sv = *(const float4*)(SA + s * kStRow + 4 * k4);
          C0[s] = fmaf(sv.x, u2[4 * k4 + 0].x, C0[s]);
          C0[s] = fmaf(sv.y, u2[4 * k4 + 1].x, C0[s]);
          C0[s] = fmaf(sv.z, u2[4 * k4 + 2].x, C0[s]);
          C0[s] = fmaf(sv.w, u2[4 * k4 + 3].x, C0[s]);
          C1[s] = fmaf(sv.x, u2[4 * k4 + 0].y, C1[s]);
          C1[s] = fmaf(sv.y, u2[4 * k4 + 1].y, C1[s]);
          C1[s] = fmaf(sv.z, u2[4 * k4 + 2].y, C1[s]);
          C1[s] = fmaf(sv.w, u2[4 * k4 + 3].y, C1[s]);
        }
      }
#pragma unroll
      for (int s = 0; s < 8; ++s) {
        C0[s] = dpp_add<0xB1>(C0[s]);  C1[s] = dpp_add<0xB1>(C1[s]);
        C0[s] = dpp_add<0x4E>(C0[s]);  C1[s] = dpp_add<0x4E>(C1[s]);
        C0[s] = dpp_add<0x141>(C0[s]); C1[s] = dpp_add<0x141>(C1[s]);
      }
      caA = C0[0]; cbA = C1[0];
#pragma unroll
      for (int s = 1; s < 8; ++s) {
        if (q == s) { caA = C0[s]; cbA = C1[s]; }
      }
    }
    if (dB) {
      float C0[8], C1[8];
#pragma unroll
      for (int s = 0; s < 8; ++s) { C0[s] = 0.f; C1[s] = 0.f; }
#pragma unroll
      for (int k4 = 0; k4 < 8; ++k4) {
#pragma unroll
        for (int s = 0; s < 8; ++s) {
          float4 sv = *(const float4*)(SB + s * kStRow + 4 * k4);
          C0[s] = fmaf(sv.x, u2[4 * k4 + 0].x, C0[s]);
          C0[s] = fmaf(sv.y, u2[4 * k4 + 1].x, C0[s]);
          C0[s] = fmaf(sv.z, u2[4 * k4 + 2].x, C0[s]);
          C0[s] = fmaf(sv.w, u2[4 * k4 + 3].x, C0[s]);
          C1[s] = fmaf(sv.x, u2[4 * k4 + 0].y, C1[s]);
          C1[s] = fmaf(sv.y, u2[4 * k4 + 1].y, C1[s]);
          C1[s] = fmaf(sv.z, u2[4 * k4 + 2].y, C1[s]);
          C1[s] = fmaf(sv.w, u2[4 * k4 + 3].y, C1[s]);
        }
      }
#pragma unroll
      for (int s = 0; s < 8; ++s) {
        C0[s] = dpp_add<0xB1>(C0[s]);  C1[s] = dpp_add<0xB1>(C1[s]);
        C0[s] = dpp_add<0x4E>(C0[s]);  C1[s] = dpp_add<0x4E>(C1[s]);
        C0[s] = dpp_add<0x141>(C0[s]); C1[s] = dpp_add<0x141>(C1[s]);
      }
      caB = C0[0]; cbB = C1[0];
#pragma unroll
      for (int s = 1; s < 8; ++s) {
        if (q == s) { caB = C0[s]; cbB = C1[s]; }
      }
    }

    // phase-2 operands (latency drains at the barrier)
    const float2 xwA = *(const float2*)(XW + baseA + c0);
    const float gkA = GK[((size_t)bA * kT + t) * kS + q];
    float2 xwB = make_float2(0.f, 0.f);
    float gkB = 0.f;
    if (dB) {
      xwB = *(const float2*)(XW + baseB + c0);
      gkB = GK[((size_t)bB * kT + t) * kS + q];
    }

    __syncthreads();  // B1: redG complete; all state reads done

    // ================= Phase 2 (reads redG; writes state + redN) ==========
    {
      const float* rg = redGA + q * kRedRow + hoff;
      float4 ra = *(const float4*)(rg);
      float4 rb = *(const float4*)(rg + 4);
      float gh = ((ra.x + ra.y) + (ra.z + ra.w)) + ((rb.x + rb.y) + (rb.z + rb.w));
      gh += __shfl_xor(gh, 8, 64);
      float gs = fmaf(gh, inhA, gkA + gb);
      float g = 1.f / (1.f + __expf(-gs));
      float t0 = fmaf(caA, inhA, kvq.x) + xwA.x; t0 = t0 > 0.f ? t0 : (__expf(t0) - 1.f);
      float t1 = fmaf(cbA, inhA, kvq.y) + xwA.y; t1 = t1 > 0.f ? t1 : (__expf(t1) - 1.f);
      float h0 = fmaf(g, t0, stA2.x * inhA);
      float h1 = fmaf(g, t1, stA2.y * inhA);
      float pn = fmaf(h0, h0, h1 * h1);
      pn += __shfl_xor(pn, 8, 64);
      pn += __shfl_xor(pn, 16, 64);
      pn += __shfl_xor(pn, 32, 64);
      if (lane < 8) redNA[lane * kRedRow + w] = pn;
      *(float2*)stpA = make_float2(h0, h1);  // store UNNORMALIZED
    }
    if (dB) {
      const float* rg = redGB + q * kRedRow + hoff;
      float4 ra = *(const float4*)(rg);
      float4 rb = *(const float4*)(rg + 4);
      float gh = ((ra.x + ra.y) + (ra.z + ra.w)) + ((rb.x + rb.y) + (rb.z + rb.w));
      gh += __shfl_xor(gh, 8, 64);
      float gs = fmaf(gh, inhB, gkB + gb);
      float g = 1.f / (1.f + __expf(-gs));
      float t0 = fmaf(caB, inhB, kvq.x) + xwB.x; t0 = t0 > 0.f ? t0 : (__expf(t0) - 1.f);
      float t1 = fmaf(cbB, inhB, kvq.y) + xwB.y; t1 = t1 > 0.f ? t1 : (__expf(t1) - 1.f);
      float h0 = fmaf(g, t0, stB2.x * inhB);
      float h1 = fmaf(g, t1, stB2.y * inhB);
      float pn = fmaf(h0, h0, h1 * h1);
      pn += __shfl_xor(pn, 8, 64);
      pn += __shfl_xor(pn, 16, 64);
      pn += __shfl_xor(pn, 32, 64);
      if (lane < 8) redNB[lane * kRedRow + w] = pn;
      *(float2*)stpB = make_float2(h0, h1);
    }
    __syncthreads();  // B2: new state + redN visible for next step
  }

  // final per-row inverse norms
  if (tid < 8) {
    float s = 0.f;
    for (int ww = 0; ww < 16; ++ww) s += redNA[tid * kRedRow + ww];
    inhFA[tid] = 1.f / fmaxf(sqrtf(s), 1e-12f);
  } else if (tid < 16) {
    const int s8 = tid - 8;
    float s = 0.f;
    for (int ww = 0; ww < 16; ++ww) s += redNB[s8 * kRedRow + ww];
    inhFB[s8] = 1.f / fmaxf(sqrtf(s), 1e-12f);
  }
  __syncthreads();

  // final states -> out (apply deferred normalization)
  for (int i = tid; i < kS * kD; i += 1024) {
    int s = i >> 8, dd = i & 255;
    int pa = s * kStRow + physk(dd);
    out[(size_t)bA * kS * kD + i] = StA[pa] * inhFA[s];
    out[(size_t)bB * kS * kD + i] = StB[pa] * inhFB[s];
  }
}

extern "C" void kernel_launch(void* const* d_in, const int* in_sizes, int n_in,
                              void* d_out, int out_size, void* d_ws, size_t ws_size,
                              hipStream_t stream) {
  const float* inputs     = (const float*)d_in[0];
  const int*   lengths    = (const int*)  d_in[1];
  const float* keys       = (const float*)d_in[2];
  const float* U          = (const float*)d_in[3];
  const float* V          = (const float*)d_in[4];
  const float* W          = (const float*)d_in[5];
  const float* gate_bias  = (const float*)d_in[6];
  const float* state_bias = (const float*)d_in[7];

  const size_t xw_elems = (size_t)kB * kT * kD;
  const size_t gk_elems = (size_t)kB * kT * kS;
  float* XW = (float*)d_ws;
  float* GK = (float*)d_ws + xw_elems;
  int*   order = (int*)((float*)d_ws + xw_elems + gk_elems);

  sort_lengths_kernel<<<dim3(1), dim3(512), 0, stream>>>(lengths, order);
  xw_gemm_kernel<<<dim3((kB * kT) / 32), dim3(256), 0, stream>>>(inputs, W, lengths, XW);
  gk_kernel<<<dim3(kB), dim3(256), 0, stream>>>(inputs, keys, lengths, GK);
  dynmem_rec8_kernel<<<dim3(kB / 2), dim3(1024), 0, stream>>>(
      inputs, lengths, keys, U, V, gate_bias, state_bias, XW, GK, order, (float*)d_out);
}